// Round 6
// baseline (1119.241 us; speedup 1.0000x reference)
//
#include <hip/hip_runtime.h>
#include <hip/hip_fp16.h>
#include <hip/hip_cooperative_groups.h>
#include <math.h>

namespace cg = cooperative_groups;

#define N_SRC   50000
#define N_SAMP  50000
#define N_TOTAL 200000
#define NE      1600000
#define D       256

// Edges grouped by (row, col>>CBSHIFT), contiguous per row (4-padded regions).
#define CBSHIFT 12
#define NB      13                 // ceil(50000 / 4096)
#define NCELL   (N_SAMP * NB)      // 650,000

typedef unsigned short ushort;
typedef unsigned int   uint;
using bf16x8 = __attribute__((ext_vector_type(8))) short;
using f32x4v = __attribute__((ext_vector_type(4))) float;

// ---- nontemporal helpers ----
__device__ __forceinline__ float4 ntload4(const float* p) {
    f32x4v t = __builtin_nontemporal_load((const f32x4v*)p);
    return make_float4(t.x, t.y, t.z, t.w);
}
__device__ __forceinline__ void ntstore4(float* p, float4 v) {
    f32x4v t; t.x = v.x; t.y = v.y; t.z = v.z; t.w = v.w;
    __builtin_nontemporal_store(t, (f32x4v*)p);
}

// ---- bf16 split helpers ----
__device__ __forceinline__ ushort bf16_rne(float f) {
    uint u = __float_as_uint(f);
    uint r = u + 0x7FFFu + ((u >> 16) & 1u);
    return (ushort)(r >> 16);
}
__device__ __forceinline__ float bf16_tof(ushort h) {
    return __uint_as_float(((uint)h) << 16);
}

// ---- fp16 x gather load: 8 B/lane -> float4 ----
__device__ __forceinline__ float4 xload4h(const __half* p) {
    int2 r = *(const int2*)p;
    __half2 h0 = *(__half2*)&r.x;
    __half2 h1 = *(__half2*)&r.y;
    float2 f0 = __half22float2(h0);
    float2 f1 = __half22float2(h1);
    return make_float4(f0.x, f0.y, f1.x, f1.y);
}

// ---- packed edge: low16 = col, high16 = fp16 val ----
__device__ __forceinline__ void eunpack(uint e, int& col, float& val) {
    col = (int)(e & 0xFFFFu);
    val = __half2float(__ushort_as_half((ushort)(e >> 16)));
}

// ---- Pass A (cooperative): init | x->fp16 | Wsplit || count+owner || rowalloc || scatter
__global__ __launch_bounds__(256, 4) void k_build(
    const float* __restrict__ x, __half* __restrict__ xh,
    const float* __restrict__ W, ushort* __restrict__ Wt_hi, ushort* __restrict__ Wt_lo,
    const int* __restrict__ adj_row, const int* __restrict__ adj_col,
    const float* __restrict__ adj_val, const int* __restrict__ nodes,
    int* __restrict__ cellcnt, int* __restrict__ cellcur,
    int* __restrict__ rowptr, int* __restrict__ rowcnt,
    int* __restrict__ gtotal, int* __restrict__ owner, uint* __restrict__ bucket)
{
    cg::grid_group grid = cg::this_grid();
    int tid = blockIdx.x * 256 + threadIdx.x;
    int nth = gridDim.x * 256;

    // ---- phase 0: init + x->fp16 + W split/transpose ----
    for (int i = tid; i < NCELL; i += nth) cellcnt[i] = 0;
    for (int i = tid; i < N_TOTAL; i += nth) owner[i] = -1;
    if (tid == 0) *gtotal = 0;
    for (int i = tid; i < (N_SRC * D) / 8; i += nth) {
        float4 a = ntload4(x + (size_t)i * 8);        // read-once
        float4 c = ntload4(x + (size_t)i * 8 + 4);
        __half2 h0 = __floats2half2_rn(a.x, a.y);
        __half2 h1 = __floats2half2_rn(a.z, a.w);
        __half2 h2 = __floats2half2_rn(c.x, c.y);
        __half2 h3 = __floats2half2_rn(c.z, c.w);
        int4 w;
        w.x = *(int*)&h0; w.y = *(int*)&h1; w.z = *(int*)&h2; w.w = *(int*)&h3;
        *(int4*)(xh + (size_t)i * 8) = w;
    }
    for (int i = tid; i < D * D; i += nth) {
        int k = i >> 8;
        int n = i & 255;
        float f = W[i];
        ushort h = bf16_rne(f);
        ushort l = bf16_rne(f - bf16_tof(h));
        Wt_hi[n * D + k] = h;
        Wt_lo[n * D + k] = l;
    }
    grid.sync();

    // ---- phase 1: per-cell counts + owner (last-write-wins) ----
    for (int i = tid; i < NE; i += nth) {
        int row = __builtin_nontemporal_load(adj_row + i);
        int col = __builtin_nontemporal_load(adj_col + i);
        atomicAdd(&cellcnt[row * NB + (col >> CBSHIFT)], 1);
    }
    for (int i = tid; i < N_SAMP; i += nth) {
        atomicMax(&owner[nodes[i]], i);
    }
    grid.sync();

    // ---- phase 2: contiguous 4-padded region per row ----
    for (int r = tid; r < N_SAMP; r += nth) {
        int pref[NB];
        int sum = 0;
        #pragma unroll
        for (int cb = 0; cb < NB; ++cb) {
            pref[cb] = sum;
            sum += cellcnt[r * NB + cb];
        }
        int base = atomicAdd(gtotal, (sum + 3) & ~3);   // 16 B-aligned regions
        rowptr[r] = base;
        rowcnt[r] = sum;
        #pragma unroll
        for (int cb = 0; cb < NB; ++cb)
            cellcur[r * NB + cb] = base + pref[cb];
    }
    grid.sync();

    // ---- phase 3: scatter packed 4 B edges ----
    for (int i = tid; i < NE; i += nth) {
        int   row = __builtin_nontemporal_load(adj_row + i);
        int   col = __builtin_nontemporal_load(adj_col + i);
        float val = __builtin_nontemporal_load(adj_val + i);
        uint  e   = (uint)col | ((uint)__half_as_ushort(__float2half_rn(val)) << 16);
        int pos = atomicAdd(&cellcur[row * NB + (col >> CBSHIFT)], 1);
        bucket[pos] = e;
    }
}

// ---- Pass B: SpMM (fp16 x, 4 B edges, 8-wide ILP) + blend + new_y ----
__global__ __launch_bounds__(256) void k_spmm_blend(
    const __half* __restrict__ xh, const uint* __restrict__ bucket,
    const int* __restrict__ rowptr, const int* __restrict__ rowcnt,
    const int* __restrict__ nodes, const int* __restrict__ owner,
    const float* __restrict__ y_buf, float* __restrict__ feat, float* __restrict__ newy)
{
    int wave = threadIdx.x >> 6;
    int lane = threadIdx.x & 63;
    int row  = blockIdx.x * 4 + wave;      // grid exact: always < N_SAMP
    int off  = lane * 4;

    int cnt = rowcnt[row];
    const uint* bk = bucket + rowptr[row];     // 16 B aligned
    float4 acc = make_float4(0.f, 0.f, 0.f, 0.f);
    int j = 0;
    for (; j + 7 < cnt; j += 8) {
        uint4 ea = *(const uint4*)(bk + j);
        uint4 eb = *(const uint4*)(bk + j + 4);
        int c0, c1, c2, c3, c4, c5, c6, c7;
        float v0, v1, v2, v3, v4, v5, v6, v7;
        eunpack(ea.x, c0, v0); eunpack(ea.y, c1, v1);
        eunpack(ea.z, c2, v2); eunpack(ea.w, c3, v3);
        eunpack(eb.x, c4, v4); eunpack(eb.y, c5, v5);
        eunpack(eb.z, c6, v6); eunpack(eb.w, c7, v7);
        float4 x0 = xload4h(xh + (size_t)c0 * D + off);
        float4 x1 = xload4h(xh + (size_t)c1 * D + off);
        float4 x2 = xload4h(xh + (size_t)c2 * D + off);
        float4 x3 = xload4h(xh + (size_t)c3 * D + off);
        float4 x4 = xload4h(xh + (size_t)c4 * D + off);
        float4 x5 = xload4h(xh + (size_t)c5 * D + off);
        float4 x6 = xload4h(xh + (size_t)c6 * D + off);
        float4 x7 = xload4h(xh + (size_t)c7 * D + off);
        acc.x += v0 * x0.x + v1 * x1.x + v2 * x2.x + v3 * x3.x
               + v4 * x4.x + v5 * x5.x + v6 * x6.x + v7 * x7.x;
        acc.y += v0 * x0.y + v1 * x1.y + v2 * x2.y + v3 * x3.y
               + v4 * x4.y + v5 * x5.y + v6 * x6.y + v7 * x7.y;
        acc.z += v0 * x0.z + v1 * x1.z + v2 * x2.z + v3 * x3.z
               + v4 * x4.z + v5 * x5.z + v6 * x6.z + v7 * x7.z;
        acc.w += v0 * x0.w + v1 * x1.w + v2 * x2.w + v3 * x3.w
               + v4 * x4.w + v5 * x5.w + v6 * x6.w + v7 * x7.w;
    }
    for (; j < cnt; ++j) {
        int c0; float v0;
        eunpack(bk[j], c0, v0);
        float4 x0 = xload4h(xh + (size_t)c0 * D + off);
        acc.x += v0 * x0.x; acc.y += v0 * x0.y;
        acc.z += v0 * x0.z; acc.w += v0 * x0.w;
    }
    int node = nodes[row];
    float4 yv = ntload4(y_buf + (size_t)node * D + off);   // NT: proven round-4 config
    float4 f;
    f.x = 0.9f * yv.x + 0.1f * acc.x;
    f.y = 0.9f * yv.y + 0.1f * acc.y;
    f.z = 0.9f * yv.z + 0.1f * acc.z;
    f.w = 0.9f * yv.w + 0.1f * acc.w;
    *(float4*)(feat + (size_t)row * D + off) = f;   // re-read by gemm: keep cached
    if (owner[node] == row)
        ntstore4(newy + (size_t)node * D + off, f);

    // fused decay rows (owner < 0): wave `row` owns newy rows 4row..4row+3
    int base = row * 4;
    int4 ow = *(const int4*)&owner[base];
    #pragma unroll
    for (int k = 0; k < 4; ++k) {
        int o = (k == 0) ? ow.x : (k == 1) ? ow.y : (k == 2) ? ow.z : ow.w;
        if (o < 0) {
            int r = base + k;
            float4 y = ntload4(y_buf + (size_t)r * D + off);
            ntstore4(newy + (size_t)r * D + off,
                     make_float4(0.9f * y.x, 0.9f * y.y, 0.9f * y.z, 0.9f * y.w));
        }
    }
}

// ---- Pass C: MFMA gemm (3-term bf16 split) + bias + ELU + row-norm, fused ----
__global__ __launch_bounds__(256) void k_gemm_elu_norm(
    float* __restrict__ io, const ushort* __restrict__ Wt_hi,
    const ushort* __restrict__ Wt_lo, const float* __restrict__ b,
    const float* __restrict__ scale, const float* __restrict__ offset)
{
    __shared__ ushort Fhi[32][264], Flo[32][264];
    __shared__ ushort Wh[256][40],  Wl[256][40];
    __shared__ float  red[2][2][16][2];

    int tid  = threadIdx.x;
    int w    = tid >> 6;
    int l    = tid & 63;
    int g    = l >> 4;
    int c16  = l & 15;
    int mt   = w & 1;
    int nh   = w >> 1;
    int r0   = blockIdx.x * 32;

    {
        int m  = tid >> 3;
        int c0 = (tid & 7) * 32;
        int r  = r0 + m;
        #pragma unroll
        for (int i = 0; i < 8; ++i) {
            float4 v = (r < N_SAMP) ? *(const float4*)(io + (size_t)r * D + c0 + i * 4)
                                    : make_float4(0.f, 0.f, 0.f, 0.f);
            ushort h0 = bf16_rne(v.x), h1 = bf16_rne(v.y);
            ushort h2 = bf16_rne(v.z), h3 = bf16_rne(v.w);
            ushort l0 = bf16_rne(v.x - bf16_tof(h0));
            ushort l1 = bf16_rne(v.y - bf16_tof(h1));
            ushort l2 = bf16_rne(v.z - bf16_tof(h2));
            ushort l3 = bf16_rne(v.w - bf16_tof(h3));
            int c = c0 + i * 4;
            uint2 ph, pl;
            ph.x = (uint)h0 | ((uint)h1 << 16); ph.y = (uint)h2 | ((uint)h3 << 16);
            pl.x = (uint)l0 | ((uint)l1 << 16); pl.y = (uint)l2 | ((uint)l3 << 16);
            *(uint2*)&Fhi[m][c] = ph;
            *(uint2*)&Flo[m][c] = pl;
        }
    }

    f32x4v acc[8];
    #pragma unroll
    for (int t = 0; t < 8; ++t) acc[t] = (f32x4v)(0.f);

    for (int kt8 = 0; kt8 < 8; ++kt8) {
        int kt = kt8 * 32;
        __syncthreads();
        {
            int n = tid;
            const int4* gh = (const int4*)(Wt_hi + (size_t)n * D + kt);
            const int4* gl = (const int4*)(Wt_lo + (size_t)n * D + kt);
            #pragma unroll
            for (int i = 0; i < 4; ++i) {
                *(int4*)&Wh[n][i * 8] = gh[i];
                *(int4*)&Wl[n][i * 8] = gl[i];
            }
        }
        __syncthreads();
        int arow = mt * 16 + c16;
        bf16x8 ah = *(const bf16x8*)&Fhi[arow][kt + g * 8];
        bf16x8 al = *(const bf16x8*)&Flo[arow][kt + g * 8];
        #pragma unroll
        for (int t = 0; t < 8; ++t) {
            int n = nh * 128 + t * 16 + c16;
            bf16x8 bh = *(const bf16x8*)&Wh[n][g * 8];
            bf16x8 bl = *(const bf16x8*)&Wl[n][g * 8];
            acc[t] = __builtin_amdgcn_mfma_f32_16x16x32_bf16(ah, bh, acc[t], 0, 0, 0);
            acc[t] = __builtin_amdgcn_mfma_f32_16x16x32_bf16(al, bh, acc[t], 0, 0, 0);
            acc[t] = __builtin_amdgcn_mfma_f32_16x16x32_bf16(ah, bl, acc[t], 0, 0, 0);
        }
    }

    float bcol[8], scol[8], ocol[8];
    #pragma unroll
    for (int t = 0; t < 8; ++t) {
        int c = nh * 128 + t * 16 + c16;
        bcol[t] = b[c]; scol[t] = scale[c]; ocol[t] = offset[c];
    }
    float s[4] = {0.f, 0.f, 0.f, 0.f};
    float q[4] = {0.f, 0.f, 0.f, 0.f};
    #pragma unroll
    for (int t = 0; t < 8; ++t) {
        #pragma unroll
        for (int j = 0; j < 4; ++j) {
            float o = acc[t][j] + bcol[t];
            o = o > 0.f ? o : expf(o) - 1.f;
            acc[t][j] = o;
            s[j] += o;
            q[j] += o * o;
        }
    }
    #pragma unroll
    for (int j = 0; j < 4; ++j) {
        #pragma unroll
        for (int d2 = 1; d2 < 16; d2 <<= 1) {
            s[j] += __shfl_xor(s[j], d2, 64);
            q[j] += __shfl_xor(q[j], d2, 64);
        }
    }
    if (c16 == 0) {
        #pragma unroll
        for (int j = 0; j < 4; ++j) {
            red[mt][nh][g * 4 + j][0] = s[j];
            red[mt][nh][g * 4 + j][1] = q[j];
        }
    }
    __syncthreads();
    #pragma unroll
    for (int j = 0; j < 4; ++j) {
        int rr = g * 4 + j;
        float S = red[mt][0][rr][0] + red[mt][1][rr][0];
        float Q = red[mt][0][rr][1] + red[mt][1][rr][1];
        float mean = S * (1.0f / 256.0f);
        float var  = Q * (1.0f / 256.0f) - mean * mean + 1e-9f;
        float rstd = rsqrtf(var);
        int r = r0 + mt * 16 + rr;
        if (r < N_SAMP) {
            #pragma unroll
            for (int t = 0; t < 8; ++t) {
                int c = nh * 128 + t * 16 + c16;
                io[(size_t)r * D + c] = (acc[t][j] - mean) * scol[t] * rstd + ocol[t];
            }
        }
    }
}

extern "C" void kernel_launch(void* const* d_in, const int* in_sizes, int n_in,
                              void* d_out, int out_size, void* d_ws, size_t ws_size,
                              hipStream_t stream) {
    const float* x       = (const float*)d_in[0];
    const int*   adj_row = (const int*)  d_in[1];
    const int*   adj_col = (const int*)  d_in[2];
    const float* adj_val = (const float*)d_in[3];
    const int*   nodes   = (const int*)  d_in[4];
    const float* y_buf   = (const float*)d_in[5];
    const float* Wm      = (const float*)d_in[6];
    const float* b       = (const float*)d_in[7];
    const float* scale   = (const float*)d_in[8];
    const float* offset  = (const float*)d_in[9];

    float* out  = (float*)d_out;                  // [N_SAMP, D] (feat staged here first)
    float* newy = out + (size_t)N_SAMP * D;       // [N_TOTAL, D]

    // workspace layout (≈ 42.6 MB)
    char*   ws      = (char*)d_ws;
    int*    cellcnt = (int*)(ws);                                  // 2.6 MB
    int*    cellcur = (int*)(ws + 3 * 1024 * 1024);                // 2.6 MB
    int*    rowptr  = (int*)(ws + 6 * 1024 * 1024);                // 200 KB
    int*    rowcnt  = (int*)(ws + 6 * 1024 * 1024 + 256 * 1024);
    int*    gtotal  = (int*)(ws + 6 * 1024 * 1024 + 512 * 1024);
    int*    owner   = (int*)(ws + 7 * 1024 * 1024);                // 800 KB
    ushort* Wt_hi   = (ushort*)(ws + 8 * 1024 * 1024);             // 128 KB
    ushort* Wt_lo   = (ushort*)(ws + 8 * 1024 * 1024 + 256 * 1024);
    uint*   bucket  = (uint*)(ws + 9 * 1024 * 1024);               // 8 MB (NE + pad)
    __half* xh      = (__half*)(ws + 17 * 1024 * 1024);            // 25.6 MB

    void* bargs[] = {
        (void*)&x, (void*)&xh, (void*)&Wm, (void*)&Wt_hi, (void*)&Wt_lo,
        (void*)&adj_row, (void*)&adj_col, (void*)&adj_val, (void*)&nodes,
        (void*)&cellcnt, (void*)&cellcur, (void*)&rowptr, (void*)&rowcnt,
        (void*)&gtotal, (void*)&owner, (void*)&bucket};
    hipLaunchCooperativeKernel(k_build, dim3(1024), dim3(256), bargs, 0u, stream);

    k_spmm_blend<<<N_SAMP / 4, 256, 0, stream>>>(
        xh, bucket, rowptr, rowcnt, nodes, owner, y_buf, out, newy);
    k_gemm_elu_norm<<<(N_SAMP + 31) / 32, 256, 0, stream>>>(out, Wt_hi, Wt_lo, b, scale, offset);
}